// Round 3
// baseline (729.253 us; speedup 1.0000x reference)
//
#include <hip/hip_runtime.h>
#include <hip/hip_fp16.h>
#include <hip/hip_bf16.h>
#include <math.h>

#define L 8192
#define LOG2L 13
#define B 16
#define CIN 64
#define COUT 64
#define KK 64

#define PI_F 3.14159265358979323846f

// ---------------- kernel 1: partial per-batch min/max of |x| ----------------
__global__ __launch_bounds__(256) void k_reduce1(const float* __restrict__ xr,
                                                 const float* __restrict__ xi,
                                                 float* __restrict__ pmin,
                                                 float* __restrict__ pmax) {
    int bid = blockIdx.x;            // 1024 = 16 batches * 64 slices
    int batch = bid >> 6, slice = bid & 63;
    size_t base = (size_t)batch * CIN * L + (size_t)slice * L;
    int tid = threadIdx.x;
    float mn = 3.4e38f, mx = 0.0f;
    for (int r = 0; r < 32; ++r) {
        int idx = r * 256 + tid;
        float a = xr[base + idx], b = xi[base + idx];
        float m = sqrtf(a * a + b * b);
        mn = fminf(mn, m);
        mx = fmaxf(mx, m);
    }
    __shared__ float smn[4], smx[4];
    for (int off = 32; off >= 1; off >>= 1) {
        mn = fminf(mn, __shfl_down(mn, off));
        mx = fmaxf(mx, __shfl_down(mx, off));
    }
    int wave = tid >> 6;
    if ((tid & 63) == 0) { smn[wave] = mn; smx[wave] = mx; }
    __syncthreads();
    if (tid == 0) {
        for (int w = 1; w < 4; ++w) { mn = fminf(mn, smn[w]); mx = fmaxf(mx, smx[w]); }
        pmin[bid] = mn;
        pmax[bid] = mx;
    }
}

// ---------------- kernel 2: final min/max ----------------
__global__ __launch_bounds__(64) void k_reduce2(const float* __restrict__ pmin,
                                                const float* __restrict__ pmax,
                                                float* __restrict__ mmin,
                                                float* __restrict__ mmax) {
    int b = blockIdx.x, t = threadIdx.x;
    float mn = pmin[b * 64 + t], mx = pmax[b * 64 + t];
    for (int off = 32; off >= 1; off >>= 1) {
        mn = fminf(mn, __shfl_down(mn, off));
        mx = fmaxf(mx, __shfl_down(mx, off));
    }
    if (t == 0) { mmin[b] = mn; mmax[b] = mx; }
}

// ---------------- kernel 3: kernel FFT stats (64-pt DFT, mag+phase) ----------------
__global__ __launch_bounds__(64) void k_kstats(const float* __restrict__ kr,
                                               const float* __restrict__ ki,
                                               float* __restrict__ kmag,
                                               float* __restrict__ kph) {
    int row = blockIdx.x;   // o*64 + j  (4096 rows)
    int k = threadIdx.x;    // output frequency 0..63
    __shared__ float sr[64], si[64];
    sr[k] = kr[row * 64 + k];
    si[k] = ki[row * 64 + k];
    __syncthreads();
    float ar = 0.f, ai = 0.f;
    for (int n = 0; n < 64; ++n) {
        int m = (n * k) & 63;                       // exact mod-64 reduction
        float ang = -2.0f * PI_F * (float)m * (1.0f / 64.0f);
        float s, c;
        __sincosf(ang, &s, &c);
        ar += sr[n] * c - si[n] * s;
        ai += sr[n] * s + si[n] * c;
    }
    kmag[row * 64 + k] = sqrtf(ar * ar + ai * ai);
    kph[row * 64 + k] = atan2f(ai, ar);
}

// ---------------- kernel 4: coupling + forward DIF FFT (per row) ----------------
// output stored in DIF order: storage index p holds frequency bitrev13(p)
// x_fft stored as half2 (re,im) in d_out (exactly out_size*4 bytes)
__global__ __launch_bounds__(512) void k_fwd(const float* __restrict__ xr,
                                             const float* __restrict__ xi,
                                             const float* __restrict__ mmin_,
                                             const float* __restrict__ mmax_,
                                             __half2* __restrict__ xfft) {
    __shared__ float sRe[L];
    __shared__ float sIm[L];
    int row = blockIdx.x;          // b*64 + j
    int b = row >> 6;
    int tid = threadIdx.x;
    float mmin = mmin_[b], mmax = mmax_[b];
    float span = mmax - mmin;
    float invden = 1.0f / (span + 1e-10f);
    size_t base = (size_t)row * L;

    for (int rpt = 0; rpt < L / 512; ++rpt) {
        int idx = rpt * 512 + tid;
        float a = xr[base + idx], c = xi[base + idx];
        float m = sqrtf(a * a + c * c);
        float xn = (m - mmin) * invden;
#pragma unroll
        for (int it = 0; it < 5; ++it) xn = 3.8f * xn * (1.0f - xn);
        float mc = xn * span + mmin;
        float scale = (m > 0.0f) ? (mc / m) : 0.0f;
        sRe[idx] = a * scale;
        sIm[idx] = c * scale;
    }

    // radix-2 DIF, natural in -> bit-reversed out
    for (int s = 0; s < LOG2L; ++s) {
        int lg = LOG2L - 1 - s;
        int len = 1 << lg;
        float fstep = -PI_F / (float)len;
        __syncthreads();
        for (int rpt = 0; rpt < (L / 2) / 512; ++rpt) {
            int t = rpt * 512 + tid;
            int j = t & (len - 1);
            int idx = ((t >> lg) << (lg + 1)) | j;
            float ar = sRe[idx], ai = sIm[idx];
            float br = sRe[idx + len], bi = sIm[idx + len];
            sRe[idx] = ar + br;
            sIm[idx] = ai + bi;
            float dr = ar - br, di = ai - bi;
            float ang = fstep * (float)j;
            float sn, cs;
            __sincosf(ang, &sn, &cs);
            sRe[idx + len] = dr * cs - di * sn;
            sIm[idx + len] = dr * sn + di * cs;
        }
    }
    __syncthreads();

    for (int rpt = 0; rpt < L / 512; ++rpt) {
        int idx = rpt * 512 + tid;
        xfft[base + idx] = __floats2half2_rn(sRe[idx], sIm[idx]);
    }
}

// ---------------- kernel 5: per-frequency complex GEMM ----------------
// out_fft[b,i,p] = sum_j x_fft[b,j,p] * kint[i,j, l=bitrev(p)]   (all in DIF order)
// Two-phase chunks: cooperative staging of BOTH x-tile and kint-tile into LDS
// (batched independent gathers + batched sincos), then a pure ds_read+FMA MAC loop.
#define PB 32
#define IB 16
#define JC 4
__global__ __launch_bounds__(256, 4) void k_gemm(const __half2* __restrict__ xfft,
                                                 const float* __restrict__ kmag,
                                                 const float* __restrict__ kph,
                                                 __hip_bfloat162* __restrict__ outfft) {
    __shared__ float2 xtile[JC][B][PB];    // 16 KB
    __shared__ float2 ktile[JC][IB][PB];   // 16 KB

    int bid = blockIdx.x;          // 256 p-blocks * 4 i-blocks, i-blocks adjacent
    int ib = bid & 3;
    int pb = bid >> 2;
    int p0 = pb * PB;
    int i0 = ib * IB;
    int tid = threadIdx.x;
    int pl = tid & 31;             // p lane (stable across all staging rounds: 256 % 32 == 0)
    int g = tid >> 5;              // group 0..7, 2 i's each
    int p = p0 + pl;
    int l = (int)(__brev((unsigned)p) >> 19);   // actual frequency

    // interpolation parameters for this lane's frequency
    float pos = ((float)l + 0.5f) * ((float)KK / (float)L) - 0.5f;
    pos = fminf(fmaxf(pos, 0.0f), (float)(KK - 1));
    int i0k = (int)floorf(pos);
    int i1k = min(i0k + 1, KK - 1);
    float w = pos - (float)i0k;

    float accR[B][2], accI[B][2];
#pragma unroll
    for (int bb = 0; bb < B; ++bb) {
        accR[bb][0] = 0.f; accR[bb][1] = 0.f;
        accI[bb][0] = 0.f; accI[bb][1] = 0.f;
    }

    for (int jc = 0; jc < CIN; jc += JC) {
        __syncthreads();
        // stage x_fft[b, jc..jc+3, p-block]: 2048 points, 8 per thread, coalesced
        for (int r = 0; r < (JC * B * PB) / 256; ++r) {
            int lin = r * 256 + tid;
            int bj = lin >> 5;         // 0..63
            int jj = bj >> 4;          // 0..3
            int bb = bj & 15;
            __half2 v = xfft[((size_t)(bb * CIN + jc + jj)) * L + p0 + pl];
            xtile[jj][bb][pl] = make_float2(__low2float(v), __high2float(v));
        }
        // stage kint[i-block, jc..jc+3, p-block]: 2048 points, 8 per thread.
        // 32 independent L2 gathers issued before any dependent math.
        for (int r = 0; r < (JC * IB * PB) / 256; ++r) {
            int lin = r * 256 + tid;
            int ij = lin >> 5;         // 0..63
            int jj = ij >> 4;          // 0..3
            int ii = ij & 15;
            int kb = ((i0 + ii) * CIN + jc + jj) * KK;
            float m0 = kmag[kb + i0k], m1 = kmag[kb + i1k];
            float q0 = kph[kb + i0k],  q1 = kph[kb + i1k];
            float mm = m0 + (m1 - m0) * w;
            float ph = q0 + (q1 - q0) * w;
            float sn, cs;
            __sincosf(ph, &sn, &cs);
            ktile[jj][ii][pl] = make_float2(mm * cs, mm * sn);
        }
        __syncthreads();

#pragma unroll
        for (int jj = 0; jj < JC; ++jj) {
            float2 k0 = ktile[jj][g * 2 + 0][pl];
            float2 k1 = ktile[jj][g * 2 + 1][pl];
#pragma unroll
            for (int bb = 0; bb < B; ++bb) {
                float2 x = xtile[jj][bb][pl];
                accR[bb][0] += x.x * k0.x - x.y * k0.y;
                accI[bb][0] += x.x * k0.y + x.y * k0.x;
                accR[bb][1] += x.x * k1.x - x.y * k1.y;
                accI[bb][1] += x.x * k1.y + x.y * k1.x;
            }
        }
    }

#pragma unroll
    for (int q = 0; q < 2; ++q) {
        int i = i0 + g * 2 + q;
#pragma unroll
        for (int bb = 0; bb < B; ++bb) {
            __hip_bfloat162 o;
            o.x = __float2bfloat16(accR[bb][q]);
            o.y = __float2bfloat16(accI[bb][q]);
            outfft[((size_t)(bb * COUT + i)) * L + p] = o;
        }
    }
}

// ---------------- kernel 6: inverse DIT FFT + activation (real part only) ----------------
__global__ __launch_bounds__(512) void k_ifft(const __hip_bfloat162* __restrict__ outfft,
                                              const float* __restrict__ alpha_,
                                              float* __restrict__ out) {
    __shared__ float sRe[L];
    __shared__ float sIm[L];
    int row = blockIdx.x;          // b*64 + i
    int tid = threadIdx.x;
    float alpha = alpha_[0];
    size_t base = (size_t)row * L;

    for (int rpt = 0; rpt < L / 512; ++rpt) {
        int idx = rpt * 512 + tid;
        __hip_bfloat162 v = outfft[base + idx];
        sRe[idx] = __bfloat162float(v.x);
        sIm[idx] = __bfloat162float(v.y);
    }

    // radix-2 DIT inverse, bit-reversed in -> natural out, +i twiddles
    for (int s = 0; s < LOG2L; ++s) {
        int len = 1 << s;
        float fstep = PI_F / (float)len;
        __syncthreads();
        for (int rpt = 0; rpt < (L / 2) / 512; ++rpt) {
            int t = rpt * 512 + tid;
            int j = t & (len - 1);
            int idx = ((t >> s) << (s + 1)) | j;
            float ang = fstep * (float)j;
            float sn, cs;
            __sincosf(ang, &sn, &cs);
            float br = sRe[idx + len], bi = sIm[idx + len];
            float tr = br * cs - bi * sn;
            float ti = br * sn + bi * cs;
            float ar = sRe[idx], ai = sIm[idx];
            sRe[idx] = ar + tr;
            sIm[idx] = ai + ti;
            sRe[idx + len] = ar - tr;
            sIm[idx + len] = ai - ti;
        }
    }
    __syncthreads();

    const float invN = 1.0f / (float)L;
    for (int rpt = 0; rpt < L / 512; ++rpt) {
        int idx = rpt * 512 + tid;
        float act = sinf(alpha * (float)idx);
        out[base + idx] = sRe[idx] * act * invN;   // real part only
    }
}

// ---------------- launch ----------------
extern "C" void kernel_launch(void* const* d_in, const int* in_sizes, int n_in,
                              void* d_out, int out_size, void* d_ws, size_t ws_size,
                              hipStream_t stream) {
    const float* xr = (const float*)d_in[0];
    const float* xi = (const float*)d_in[1];
    const float* kr = (const float*)d_in[2];
    const float* ki = (const float*)d_in[3];
    const float* alpha = (const float*)d_in[4];
    float* out = (float*)d_out;

    // ws layout (total ~35.7 MB):
    //   [0, 33.5MB)   out_fft as bf16x2 (B*COUT*L complex)
    //   then kmag, kph (COUT*CIN*KK f32 each), then reduce scratch
    char* ws = (char*)d_ws;
    size_t OFFT_BYTES = (size_t)B * COUT * L * 4;          // 33,554,432
    __hip_bfloat162* outfft = (__hip_bfloat162*)ws;
    float* kmag = (float*)(ws + OFFT_BYTES);
    float* kph  = (float*)(ws + OFFT_BYTES + (size_t)COUT * CIN * KK * 4);
    float* pmin = (float*)(ws + OFFT_BYTES + (size_t)2 * COUT * CIN * KK * 4);
    float* pmax = pmin + 1024;
    float* mmin = pmax + 1024;
    float* mmax = mmin + 16;

    __half2* xfft = (__half2*)d_out;   // exactly out_size*4 bytes; overwritten by k_ifft

    hipLaunchKernelGGL(k_reduce1, dim3(1024), dim3(256), 0, stream, xr, xi, pmin, pmax);
    hipLaunchKernelGGL(k_reduce2, dim3(16), dim3(64), 0, stream, pmin, pmax, mmin, mmax);
    hipLaunchKernelGGL(k_kstats, dim3(4096), dim3(64), 0, stream, kr, ki, kmag, kph);
    hipLaunchKernelGGL(k_fwd, dim3(1024), dim3(512), 0, stream, xr, xi, mmin, mmax, xfft);
    hipLaunchKernelGGL(k_gemm, dim3(1024), dim3(256), 0, stream, xfft, kmag, kph, outfft);
    hipLaunchKernelGGL(k_ifft, dim3(1024), dim3(512), 0, stream, outfft, alpha, out);
}

// Round 4
// 411.686 us; speedup vs baseline: 1.7714x; 1.7714x over previous
//
#include <hip/hip_runtime.h>
#include <hip/hip_fp16.h>
#include <hip/hip_bf16.h>
#include <math.h>

#define L 8192
#define LOG2L 13
#define B 16
#define CIN 64
#define COUT 64
#define KK 64

#define PI_F 3.14159265358979323846f

// XOR swizzle for the bit-reversal scatter phase: bijective involution,
// spreads the 32-way bank collision of bitrev-scatter into <=2-way.
__device__ __forceinline__ int swz(int n) { return n ^ ((n >> 8) & 31); }

// ---------------- kernel 1: partial per-batch min/max of |x| ----------------
__global__ __launch_bounds__(256) void k_reduce1(const float* __restrict__ xr,
                                                 const float* __restrict__ xi,
                                                 float* __restrict__ pmin,
                                                 float* __restrict__ pmax) {
    int bid = blockIdx.x;            // 1024 = 16 batches * 64 slices
    int batch = bid >> 6, slice = bid & 63;
    size_t base = (size_t)batch * CIN * L + (size_t)slice * L;
    int tid = threadIdx.x;
    float mn = 3.4e38f, mx = 0.0f;
    for (int r = 0; r < 32; ++r) {
        int idx = r * 256 + tid;
        float a = xr[base + idx], b = xi[base + idx];
        float m = sqrtf(a * a + b * b);
        mn = fminf(mn, m);
        mx = fmaxf(mx, m);
    }
    __shared__ float smn[4], smx[4];
    for (int off = 32; off >= 1; off >>= 1) {
        mn = fminf(mn, __shfl_down(mn, off));
        mx = fmaxf(mx, __shfl_down(mx, off));
    }
    int wave = tid >> 6;
    if ((tid & 63) == 0) { smn[wave] = mn; smx[wave] = mx; }
    __syncthreads();
    if (tid == 0) {
        for (int w = 1; w < 4; ++w) { mn = fminf(mn, smn[w]); mx = fmaxf(mx, smx[w]); }
        pmin[bid] = mn;
        pmax[bid] = mx;
    }
}

// ---------------- kernel 2: final min/max ----------------
__global__ __launch_bounds__(64) void k_reduce2(const float* __restrict__ pmin,
                                                const float* __restrict__ pmax,
                                                float* __restrict__ mmin,
                                                float* __restrict__ mmax) {
    int b = blockIdx.x, t = threadIdx.x;
    float mn = pmin[b * 64 + t], mx = pmax[b * 64 + t];
    for (int off = 32; off >= 1; off >>= 1) {
        mn = fminf(mn, __shfl_down(mn, off));
        mx = fmaxf(mx, __shfl_down(mx, off));
    }
    if (t == 0) { mmin[b] = mn; mmax[b] = mx; }
}

// ---------------- kernel 3: kernel FFT stats (64-pt DFT, mag+phase) ----------------
__global__ __launch_bounds__(64) void k_kstats(const float* __restrict__ kr,
                                               const float* __restrict__ ki,
                                               float* __restrict__ kmag,
                                               float* __restrict__ kph) {
    int row = blockIdx.x;   // o*64 + j  (4096 rows)
    int k = threadIdx.x;    // output frequency 0..63
    __shared__ float sr[64], si[64];
    sr[k] = kr[row * 64 + k];
    si[k] = ki[row * 64 + k];
    __syncthreads();
    float ar = 0.f, ai = 0.f;
    for (int n = 0; n < 64; ++n) {
        int m = (n * k) & 63;                       // exact mod-64 reduction
        float ang = -2.0f * PI_F * (float)m * (1.0f / 64.0f);
        float s, c;
        __sincosf(ang, &s, &c);
        ar += sr[n] * c - si[n] * s;
        ai += sr[n] * s + si[n] * c;
    }
    kmag[row * 64 + k] = sqrtf(ar * ar + ai * ai);
    kph[row * 64 + k] = atan2f(ai, ar);
}

// ---------------- kernel 4: coupling + forward DIF FFT + bitrev permute ----------------
// x_fft written in NATURAL frequency order as half2 into d_out.
__global__ __launch_bounds__(512) void k_fwd(const float* __restrict__ xr,
                                             const float* __restrict__ xi,
                                             const float* __restrict__ mmin_,
                                             const float* __restrict__ mmax_,
                                             __half2* __restrict__ xfft) {
    __shared__ float sRe[L];
    __shared__ float sIm[L];
    int row = blockIdx.x;          // b*64 + j
    int b = row >> 6;
    int tid = threadIdx.x;
    float mmin = mmin_[b], mmax = mmax_[b];
    float span = mmax - mmin;
    float invden = 1.0f / (span + 1e-10f);
    size_t base = (size_t)row * L;

    for (int rpt = 0; rpt < L / 512; ++rpt) {
        int idx = rpt * 512 + tid;
        float a = xr[base + idx], c = xi[base + idx];
        float m = sqrtf(a * a + c * c);
        float xn = (m - mmin) * invden;
#pragma unroll
        for (int it = 0; it < 5; ++it) xn = 3.8f * xn * (1.0f - xn);
        float mc = xn * span + mmin;
        float scale = (m > 0.0f) ? (mc / m) : 0.0f;
        sRe[idx] = a * scale;
        sIm[idx] = c * scale;
    }

    // radix-2 DIF, natural in -> bit-reversed out (storage p holds freq bitrev(p))
    for (int s = 0; s < LOG2L; ++s) {
        int lg = LOG2L - 1 - s;
        int len = 1 << lg;
        float fstep = -PI_F / (float)len;
        __syncthreads();
        for (int rpt = 0; rpt < (L / 2) / 512; ++rpt) {
            int t = rpt * 512 + tid;
            int j = t & (len - 1);
            int idx = ((t >> lg) << (lg + 1)) | j;
            float ar = sRe[idx], ai = sIm[idx];
            float br = sRe[idx + len], bi = sIm[idx + len];
            sRe[idx] = ar + br;
            sIm[idx] = ai + bi;
            float dr = ar - br, di = ai - bi;
            float ang = fstep * (float)j;
            float sn, cs;
            __sincosf(ang, &sn, &cs);
            sRe[idx + len] = dr * cs - di * sn;
            sIm[idx + len] = dr * sn + di * cs;
        }
    }
    __syncthreads();

    // in-LDS bit-reversal permute (swizzled scatter; bijective, race-free)
    float vr[16], vi[16];
#pragma unroll
    for (int r = 0; r < 16; ++r) {
        int idx = r * 512 + tid;
        vr[r] = sRe[idx]; vi[r] = sIm[idx];
    }
    __syncthreads();
#pragma unroll
    for (int r = 0; r < 16; ++r) {
        int idx = r * 512 + tid;
        int n = (int)(__brev((unsigned)idx) >> 19);   // target natural freq
        int a = swz(n);
        sRe[a] = vr[r]; sIm[a] = vi[r];
    }
    __syncthreads();

#pragma unroll
    for (int r = 0; r < 16; ++r) {
        int n = r * 512 + tid;
        int a = swz(n);
        xfft[base + n] = __floats2half2_rn(sRe[a], sIm[a]);
    }
}

// ---------------- kernel 5: per-frequency complex GEMM (natural order) ----------------
// out_fft[b,i,l] = sum_j x_fft[b,j,l] * kint[i,j,l]
// l = p (natural): i0k is uniform within every 32-aligned p-block -> table loads broadcast.
// Per-thread blocking: 4 i's x 8 b's (64 acc VGPRs), 48 b64 LDS reads per 512 FMA.
#define PB 32
#define IB 16
#define JC 4
__global__ __launch_bounds__(256, 4) void k_gemm(const __half2* __restrict__ xfft,
                                                 const float* __restrict__ kmag,
                                                 const float* __restrict__ kph,
                                                 __hip_bfloat162* __restrict__ outfft) {
    __shared__ float2 xtile[JC][B][PB];    // 16 KB
    __shared__ float2 ktile[JC][IB][PB];   // 16 KB

    int bid = blockIdx.x;          // 256 p-blocks * 4 i-blocks, i-blocks adjacent
    int ib = bid & 3;
    int pb = bid >> 2;
    int p0 = pb * PB;
    int i0 = ib * IB;
    int tid = threadIdx.x;
    int pl = tid & 31;             // p lane
    int gi = (tid >> 5) & 3;       // i-group: 4 i's each
    int gb = tid >> 7;             // b-group: 8 b's each
    int p = p0 + pl;
    int l = p;                     // natural frequency order

    // interpolation parameters (i0k/i1k wave-uniform within the block)
    float pos = ((float)l + 0.5f) * ((float)KK / (float)L) - 0.5f;
    pos = fminf(fmaxf(pos, 0.0f), (float)(KK - 1));
    int i0k = (int)floorf(pos);
    int i1k = min(i0k + 1, KK - 1);
    float w = pos - (float)i0k;

    float accR[8][4], accI[8][4];
#pragma unroll
    for (int bb = 0; bb < 8; ++bb)
#pragma unroll
        for (int q = 0; q < 4; ++q) { accR[bb][q] = 0.f; accI[bb][q] = 0.f; }

    for (int jc = 0; jc < CIN; jc += JC) {
        __syncthreads();
        // stage x_fft[b, jc..jc+3, p-block]: coalesced 128B rows
        for (int r = 0; r < (JC * B * PB) / 256; ++r) {
            int lin = r * 256 + tid;
            int bj = lin >> 5;         // 0..63
            int jj = bj >> 4;          // 0..3
            int bb = bj & 15;
            __half2 v = xfft[((size_t)(bb * CIN + jc + jj)) * L + p0 + pl];
            xtile[jj][bb][pl] = make_float2(__low2float(v), __high2float(v));
        }
        // stage kint[i-block, jc..jc+3, p-block]: table loads are wave-uniform (broadcast)
        for (int r = 0; r < (JC * IB * PB) / 256; ++r) {
            int lin = r * 256 + tid;
            int ij = lin >> 5;         // 0..63
            int jj = ij >> 4;          // 0..3
            int ii = ij & 15;
            int kb = ((i0 + ii) * CIN + jc + jj) * KK;
            float m0 = kmag[kb + i0k], m1 = kmag[kb + i1k];
            float q0 = kph[kb + i0k],  q1 = kph[kb + i1k];
            float mm = m0 + (m1 - m0) * w;
            float ph = q0 + (q1 - q0) * w;
            float sn, cs;
            __sincosf(ph, &sn, &cs);
            ktile[jj][ii][pl] = make_float2(mm * cs, mm * sn);
        }
        __syncthreads();

#pragma unroll
        for (int jj = 0; jj < JC; ++jj) {
            float2 kv[4];
#pragma unroll
            for (int q = 0; q < 4; ++q) kv[q] = ktile[jj][gi * 4 + q][pl];
#pragma unroll
            for (int bb = 0; bb < 8; ++bb) {
                float2 x = xtile[jj][gb * 8 + bb][pl];
#pragma unroll
                for (int q = 0; q < 4; ++q) {
                    accR[bb][q] += x.x * kv[q].x - x.y * kv[q].y;
                    accI[bb][q] += x.x * kv[q].y + x.y * kv[q].x;
                }
            }
        }
    }

#pragma unroll
    for (int q = 0; q < 4; ++q) {
        int i = i0 + gi * 4 + q;
#pragma unroll
        for (int bb = 0; bb < 8; ++bb) {
            int bfull = gb * 8 + bb;
            __hip_bfloat162 o;
            o.x = __float2bfloat16(accR[bb][q]);
            o.y = __float2bfloat16(accI[bb][q]);
            outfft[((size_t)(bfull * COUT + i)) * L + p] = o;
        }
    }
}

// ---------------- kernel 6: inverse DIF FFT + bitrev permute + activation ----------------
// input outfft in NATURAL frequency order; DIF inverse (+ twiddles) -> bitrev out,
// then same swizzled permute back to natural; writes real part * act / L.
__global__ __launch_bounds__(512) void k_ifft(const __hip_bfloat162* __restrict__ outfft,
                                              const float* __restrict__ alpha_,
                                              float* __restrict__ out) {
    __shared__ float sRe[L];
    __shared__ float sIm[L];
    int row = blockIdx.x;          // b*64 + i
    int tid = threadIdx.x;
    float alpha = alpha_[0];
    size_t base = (size_t)row * L;

    for (int rpt = 0; rpt < L / 512; ++rpt) {
        int idx = rpt * 512 + tid;
        __hip_bfloat162 v = outfft[base + idx];
        sRe[idx] = __bfloat162float(v.x);
        sIm[idx] = __bfloat162float(v.y);
    }

    // radix-2 DIF with POSITIVE twiddles: natural in -> bit-reversed out, computes N*x
    for (int s = 0; s < LOG2L; ++s) {
        int lg = LOG2L - 1 - s;
        int len = 1 << lg;
        float fstep = PI_F / (float)len;
        __syncthreads();
        for (int rpt = 0; rpt < (L / 2) / 512; ++rpt) {
            int t = rpt * 512 + tid;
            int j = t & (len - 1);
            int idx = ((t >> lg) << (lg + 1)) | j;
            float ar = sRe[idx], ai = sIm[idx];
            float br = sRe[idx + len], bi = sIm[idx + len];
            sRe[idx] = ar + br;
            sIm[idx] = ai + bi;
            float dr = ar - br, di = ai - bi;
            float ang = fstep * (float)j;
            float sn, cs;
            __sincosf(ang, &sn, &cs);
            sRe[idx + len] = dr * cs - di * sn;
            sIm[idx + len] = dr * sn + di * cs;
        }
    }
    __syncthreads();

    // bitrev permute to natural order (swizzled scatter)
    float vr[16], vi[16];
#pragma unroll
    for (int r = 0; r < 16; ++r) {
        int idx = r * 512 + tid;
        vr[r] = sRe[idx]; vi[r] = sIm[idx];
    }
    __syncthreads();
#pragma unroll
    for (int r = 0; r < 16; ++r) {
        int idx = r * 512 + tid;
        int n = (int)(__brev((unsigned)idx) >> 19);
        int a = swz(n);
        sRe[a] = vr[r]; sIm[a] = vi[r];
    }
    __syncthreads();

    const float invN = 1.0f / (float)L;
#pragma unroll
    for (int rpt = 0; rpt < L / 512; ++rpt) {
        int n = rpt * 512 + tid;
        float act = sinf(alpha * (float)n);
        out[base + n] = sRe[swz(n)] * act * invN;   // real part only
    }
}

// ---------------- launch ----------------
extern "C" void kernel_launch(void* const* d_in, const int* in_sizes, int n_in,
                              void* d_out, int out_size, void* d_ws, size_t ws_size,
                              hipStream_t stream) {
    const float* xr = (const float*)d_in[0];
    const float* xi = (const float*)d_in[1];
    const float* kr = (const float*)d_in[2];
    const float* ki = (const float*)d_in[3];
    const float* alpha = (const float*)d_in[4];
    float* out = (float*)d_out;

    // ws layout (total ~35.7 MB):
    //   [0, 33.5MB)   out_fft as bf16x2 (B*COUT*L complex)
    //   then kmag, kph (COUT*CIN*KK f32 each), then reduce scratch
    char* ws = (char*)d_ws;
    size_t OFFT_BYTES = (size_t)B * COUT * L * 4;          // 33,554,432
    __hip_bfloat162* outfft = (__hip_bfloat162*)ws;
    float* kmag = (float*)(ws + OFFT_BYTES);
    float* kph  = (float*)(ws + OFFT_BYTES + (size_t)COUT * CIN * KK * 4);
    float* pmin = (float*)(ws + OFFT_BYTES + (size_t)2 * COUT * CIN * KK * 4);
    float* pmax = pmin + 1024;
    float* mmin = pmax + 1024;
    float* mmax = mmin + 16;

    __half2* xfft = (__half2*)d_out;   // exactly out_size*4 bytes; overwritten by k_ifft

    hipLaunchKernelGGL(k_reduce1, dim3(1024), dim3(256), 0, stream, xr, xi, pmin, pmax);
    hipLaunchKernelGGL(k_reduce2, dim3(16), dim3(64), 0, stream, pmin, pmax, mmin, mmax);
    hipLaunchKernelGGL(k_kstats, dim3(4096), dim3(64), 0, stream, kr, ki, kmag, kph);
    hipLaunchKernelGGL(k_fwd, dim3(1024), dim3(512), 0, stream, xr, xi, mmin, mmax, xfft);
    hipLaunchKernelGGL(k_gemm, dim3(1024), dim3(256), 0, stream, xfft, kmag, kph, outfft);
    hipLaunchKernelGGL(k_ifft, dim3(1024), dim3(512), 0, stream, outfft, alpha, out);
}

// Round 5
// 404.382 us; speedup vs baseline: 1.8034x; 1.0181x over previous
//
#include <hip/hip_runtime.h>
#include <hip/hip_fp16.h>
#include <hip/hip_bf16.h>
#include <math.h>

#define L 8192
#define LOG2L 13
#define B 16
#define CIN 64
#define COUT 64
#define KK 64

#define PI_F 3.14159265358979323846f

// XOR swizzle for the bit-reversal scatter phase: bijective involution,
// spreads the 32-way bank collision of bitrev-scatter into <=2-way.
__device__ __forceinline__ int swz(int n) { return n ^ ((n >> 8) & 31); }

// ---------------- kernel 1: partial per-batch min/max of |x| ----------------
__global__ __launch_bounds__(256) void k_reduce1(const float* __restrict__ xr,
                                                 const float* __restrict__ xi,
                                                 float* __restrict__ pmin,
                                                 float* __restrict__ pmax) {
    int bid = blockIdx.x;            // 1024 = 16 batches * 64 slices
    int batch = bid >> 6, slice = bid & 63;
    size_t base = (size_t)batch * CIN * L + (size_t)slice * L;
    int tid = threadIdx.x;
    float mn = 3.4e38f, mx = 0.0f;
    for (int r = 0; r < 32; ++r) {
        int idx = r * 256 + tid;
        float a = xr[base + idx], b = xi[base + idx];
        float m = sqrtf(a * a + b * b);
        mn = fminf(mn, m);
        mx = fmaxf(mx, m);
    }
    __shared__ float smn[4], smx[4];
    for (int off = 32; off >= 1; off >>= 1) {
        mn = fminf(mn, __shfl_down(mn, off));
        mx = fmaxf(mx, __shfl_down(mx, off));
    }
    int wave = tid >> 6;
    if ((tid & 63) == 0) { smn[wave] = mn; smx[wave] = mx; }
    __syncthreads();
    if (tid == 0) {
        for (int w = 1; w < 4; ++w) { mn = fminf(mn, smn[w]); mx = fmaxf(mx, smx[w]); }
        pmin[bid] = mn;
        pmax[bid] = mx;
    }
}

// ---------------- kernel 2: final min/max ----------------
__global__ __launch_bounds__(64) void k_reduce2(const float* __restrict__ pmin,
                                                const float* __restrict__ pmax,
                                                float* __restrict__ mmin,
                                                float* __restrict__ mmax) {
    int b = blockIdx.x, t = threadIdx.x;
    float mn = pmin[b * 64 + t], mx = pmax[b * 64 + t];
    for (int off = 32; off >= 1; off >>= 1) {
        mn = fminf(mn, __shfl_down(mn, off));
        mx = fmaxf(mx, __shfl_down(mx, off));
    }
    if (t == 0) { mmin[b] = mn; mmax[b] = mx; }
}

// ---------------- kernel 3: kernel FFT stats (64-pt DFT, mag+phase) ----------------
__global__ __launch_bounds__(64) void k_kstats(const float* __restrict__ kr,
                                               const float* __restrict__ ki,
                                               float* __restrict__ kmag,
                                               float* __restrict__ kph) {
    int row = blockIdx.x;   // o*64 + j  (4096 rows)
    int k = threadIdx.x;    // output frequency 0..63
    __shared__ float sr[64], si[64];
    sr[k] = kr[row * 64 + k];
    si[k] = ki[row * 64 + k];
    __syncthreads();
    float ar = 0.f, ai = 0.f;
    for (int n = 0; n < 64; ++n) {
        int m = (n * k) & 63;                       // exact mod-64 reduction
        float ang = -2.0f * PI_F * (float)m * (1.0f / 64.0f);
        float s, c;
        __sincosf(ang, &s, &c);
        ar += sr[n] * c - si[n] * s;
        ai += sr[n] * s + si[n] * c;
    }
    kmag[row * 64 + k] = sqrtf(ar * ar + ai * ai);
    kph[row * 64 + k] = atan2f(ai, ar);
}

// ---------------- kernel 4: coupling + forward DIF FFT + bitrev permute ----------------
// x_fft written in NATURAL frequency order as half2 into d_out.
__global__ __launch_bounds__(512) void k_fwd(const float* __restrict__ xr,
                                             const float* __restrict__ xi,
                                             const float* __restrict__ mmin_,
                                             const float* __restrict__ mmax_,
                                             __half2* __restrict__ xfft) {
    __shared__ float sRe[L];
    __shared__ float sIm[L];
    int row = blockIdx.x;          // b*64 + j
    int b = row >> 6;
    int tid = threadIdx.x;
    float mmin = mmin_[b], mmax = mmax_[b];
    float span = mmax - mmin;
    float invden = 1.0f / (span + 1e-10f);
    size_t base = (size_t)row * L;

    for (int rpt = 0; rpt < L / 512; ++rpt) {
        int idx = rpt * 512 + tid;
        float a = xr[base + idx], c = xi[base + idx];
        float m = sqrtf(a * a + c * c);
        float xn = (m - mmin) * invden;
#pragma unroll
        for (int it = 0; it < 5; ++it) xn = 3.8f * xn * (1.0f - xn);
        float mc = xn * span + mmin;
        float scale = (m > 0.0f) ? (mc / m) : 0.0f;
        sRe[idx] = a * scale;
        sIm[idx] = c * scale;
    }

    // radix-2 DIF, natural in -> bit-reversed out (storage p holds freq bitrev(p))
    for (int s = 0; s < LOG2L; ++s) {
        int lg = LOG2L - 1 - s;
        int len = 1 << lg;
        float fstep = -PI_F / (float)len;
        __syncthreads();
        for (int rpt = 0; rpt < (L / 2) / 512; ++rpt) {
            int t = rpt * 512 + tid;
            int j = t & (len - 1);
            int idx = ((t >> lg) << (lg + 1)) | j;
            float ar = sRe[idx], ai = sIm[idx];
            float br = sRe[idx + len], bi = sIm[idx + len];
            sRe[idx] = ar + br;
            sIm[idx] = ai + bi;
            float dr = ar - br, di = ai - bi;
            float ang = fstep * (float)j;
            float sn, cs;
            __sincosf(ang, &sn, &cs);
            sRe[idx + len] = dr * cs - di * sn;
            sIm[idx + len] = dr * sn + di * cs;
        }
    }
    __syncthreads();

    // in-LDS bit-reversal permute (swizzled scatter; bijective, race-free)
    float vr[16], vi[16];
#pragma unroll
    for (int r = 0; r < 16; ++r) {
        int idx = r * 512 + tid;
        vr[r] = sRe[idx]; vi[r] = sIm[idx];
    }
    __syncthreads();
#pragma unroll
    for (int r = 0; r < 16; ++r) {
        int idx = r * 512 + tid;
        int n = (int)(__brev((unsigned)idx) >> 19);   // target natural freq
        int a = swz(n);
        sRe[a] = vr[r]; sIm[a] = vi[r];
    }
    __syncthreads();

#pragma unroll
    for (int r = 0; r < 16; ++r) {
        int n = r * 512 + tid;
        int a = swz(n);
        xfft[base + n] = __floats2half2_rn(sRe[a], sIm[a]);
    }
}

// ---------------- kernel 5: per-frequency complex GEMM (natural order) ----------------
// out_fft[b,i,l] = sum_j x_fft[b,j,l] * kint[i,j,l]
// Grid decode: pb = bid & 255, ib = bid >> 8  -> the 4 i-block siblings of a
// p-block are 256 apart in dispatch index == same XCD (round-robin, 256%8==0),
// so x rows are fetched into one XCD's L2 once instead of 4 HBM/L3 refetches.
// Pipeline: x-values for chunk c+1 are prefetched into registers while chunk c's
// MAC runs; the stage phase between barriers is only ds_writes + broadcast
// table gathers + batched sincos.
#define PB 32
#define IB 16
#define JC 4
__global__ __launch_bounds__(256, 4) void k_gemm(const __half2* __restrict__ xfft,
                                                 const float* __restrict__ kmag,
                                                 const float* __restrict__ kph,
                                                 __hip_bfloat162* __restrict__ outfft) {
    __shared__ float2 xtile[JC][B][PB];    // 16 KB
    __shared__ float2 ktile[JC][IB][PB];   // 16 KB

    int bid = blockIdx.x;
    int ib = bid >> 8;             // 0..3
    int pb = bid & 255;
    int p0 = pb * PB;
    int i0 = ib * IB;
    int tid = threadIdx.x;
    int pl = tid & 31;             // p lane
    int gi = (tid >> 5) & 3;       // i-group: 4 i's each
    int gb = tid >> 7;             // b-group: 8 b's each
    int p = p0 + pl;
    int l = p;                     // natural frequency order

    // interpolation parameters (i0k/i1k wave-uniform within the block)
    float pos = ((float)l + 0.5f) * ((float)KK / (float)L) - 0.5f;
    pos = fminf(fmaxf(pos, 0.0f), (float)(KK - 1));
    int i0k = (int)floorf(pos);
    int i1k = min(i0k + 1, KK - 1);
    float w = pos - (float)i0k;

    float accR[8][4], accI[8][4];
#pragma unroll
    for (int bb = 0; bb < 8; ++bb)
#pragma unroll
        for (int q = 0; q < 4; ++q) { accR[bb][q] = 0.f; accI[bb][q] = 0.f; }

    // prefetch chunk 0 (8 coalesced half2 loads into regs)
    __half2 px[8];
#pragma unroll
    for (int r = 0; r < 8; ++r) {
        int lin = r * 256 + tid;
        int bj = lin >> 5;
        int jj = bj >> 4;
        int bb = bj & 15;
        px[r] = xfft[((size_t)(bb * CIN + jj)) * L + p0 + pl];
    }

    for (int jc = 0; jc < CIN; jc += JC) {
        __syncthreads();
        // commit prefetched x to LDS
#pragma unroll
        for (int r = 0; r < 8; ++r) {
            int lin = r * 256 + tid;
            int bj = lin >> 5;
            int jj = bj >> 4;
            int bb = bj & 15;
            xtile[jj][bb][pl] = make_float2(__low2float(px[r]), __high2float(px[r]));
        }
        // issue next chunk's prefetch (drains during this chunk's MAC)
        if (jc + JC < CIN) {
#pragma unroll
            for (int r = 0; r < 8; ++r) {
                int lin = r * 256 + tid;
                int bj = lin >> 5;
                int jj = bj >> 4;
                int bb = bj & 15;
                px[r] = xfft[((size_t)(bb * CIN + jc + JC + jj)) * L + p0 + pl];
            }
        }
        // kint: wave-uniform broadcast table loads + per-lane sincos
#pragma unroll
        for (int r = 0; r < 8; ++r) {
            int lin = r * 256 + tid;
            int ij = lin >> 5;
            int jj = ij >> 4;
            int ii = ij & 15;
            int kb = ((i0 + ii) * CIN + jc + jj) * KK;
            float m0 = kmag[kb + i0k], m1 = kmag[kb + i1k];
            float q0 = kph[kb + i0k],  q1 = kph[kb + i1k];
            float mm = m0 + (m1 - m0) * w;
            float ph = q0 + (q1 - q0) * w;
            float sn, cs;
            __sincosf(ph, &sn, &cs);
            ktile[jj][ii][pl] = make_float2(mm * cs, mm * sn);
        }
        __syncthreads();

#pragma unroll
        for (int jj = 0; jj < JC; ++jj) {
            float2 kv[4];
#pragma unroll
            for (int q = 0; q < 4; ++q) kv[q] = ktile[jj][gi * 4 + q][pl];
#pragma unroll
            for (int bb = 0; bb < 8; ++bb) {
                float2 x = xtile[jj][gb * 8 + bb][pl];
#pragma unroll
                for (int q = 0; q < 4; ++q) {
                    accR[bb][q] += x.x * kv[q].x - x.y * kv[q].y;
                    accI[bb][q] += x.x * kv[q].y + x.y * kv[q].x;
                }
            }
        }
    }

#pragma unroll
    for (int q = 0; q < 4; ++q) {
        int i = i0 + gi * 4 + q;
#pragma unroll
        for (int bb = 0; bb < 8; ++bb) {
            int bfull = gb * 8 + bb;
            __hip_bfloat162 o;
            o.x = __float2bfloat16(accR[bb][q]);
            o.y = __float2bfloat16(accI[bb][q]);
            outfft[((size_t)(bfull * COUT + i)) * L + p] = o;
        }
    }
}

// ---------------- kernel 6: inverse DIF FFT + bitrev permute + activation ----------------
// input outfft in NATURAL frequency order; DIF inverse (+ twiddles) -> bitrev out,
// then same swizzled permute back to natural; writes real part * act / L.
__global__ __launch_bounds__(512) void k_ifft(const __hip_bfloat162* __restrict__ outfft,
                                              const float* __restrict__ alpha_,
                                              float* __restrict__ out) {
    __shared__ float sRe[L];
    __shared__ float sIm[L];
    int row = blockIdx.x;          // b*64 + i
    int tid = threadIdx.x;
    float alpha = alpha_[0];
    size_t base = (size_t)row * L;

    for (int rpt = 0; rpt < L / 512; ++rpt) {
        int idx = rpt * 512 + tid;
        __hip_bfloat162 v = outfft[base + idx];
        sRe[idx] = __bfloat162float(v.x);
        sIm[idx] = __bfloat162float(v.y);
    }

    // radix-2 DIF with POSITIVE twiddles: natural in -> bit-reversed out, computes N*x
    for (int s = 0; s < LOG2L; ++s) {
        int lg = LOG2L - 1 - s;
        int len = 1 << lg;
        float fstep = PI_F / (float)len;
        __syncthreads();
        for (int rpt = 0; rpt < (L / 2) / 512; ++rpt) {
            int t = rpt * 512 + tid;
            int j = t & (len - 1);
            int idx = ((t >> lg) << (lg + 1)) | j;
            float ar = sRe[idx], ai = sIm[idx];
            float br = sRe[idx + len], bi = sIm[idx + len];
            sRe[idx] = ar + br;
            sIm[idx] = ai + bi;
            float dr = ar - br, di = ai - bi;
            float ang = fstep * (float)j;
            float sn, cs;
            __sincosf(ang, &sn, &cs);
            sRe[idx + len] = dr * cs - di * sn;
            sIm[idx + len] = dr * sn + di * cs;
        }
    }
    __syncthreads();

    // bitrev permute to natural order (swizzled scatter)
    float vr[16], vi[16];
#pragma unroll
    for (int r = 0; r < 16; ++r) {
        int idx = r * 512 + tid;
        vr[r] = sRe[idx]; vi[r] = sIm[idx];
    }
    __syncthreads();
#pragma unroll
    for (int r = 0; r < 16; ++r) {
        int idx = r * 512 + tid;
        int n = (int)(__brev((unsigned)idx) >> 19);
        int a = swz(n);
        sRe[a] = vr[r]; sIm[a] = vi[r];
    }
    __syncthreads();

    const float invN = 1.0f / (float)L;
#pragma unroll
    for (int rpt = 0; rpt < L / 512; ++rpt) {
        int n = rpt * 512 + tid;
        float act = sinf(alpha * (float)n);
        out[base + n] = sRe[swz(n)] * act * invN;   // real part only
    }
}

// ---------------- launch ----------------
extern "C" void kernel_launch(void* const* d_in, const int* in_sizes, int n_in,
                              void* d_out, int out_size, void* d_ws, size_t ws_size,
                              hipStream_t stream) {
    const float* xr = (const float*)d_in[0];
    const float* xi = (const float*)d_in[1];
    const float* kr = (const float*)d_in[2];
    const float* ki = (const float*)d_in[3];
    const float* alpha = (const float*)d_in[4];
    float* out = (float*)d_out;

    // ws layout (total ~35.7 MB):
    //   [0, 33.5MB)   out_fft as bf16x2 (B*COUT*L complex)
    //   then kmag, kph (COUT*CIN*KK f32 each), then reduce scratch
    char* ws = (char*)d_ws;
    size_t OFFT_BYTES = (size_t)B * COUT * L * 4;          // 33,554,432
    __hip_bfloat162* outfft = (__hip_bfloat162*)ws;
    float* kmag = (float*)(ws + OFFT_BYTES);
    float* kph  = (float*)(ws + OFFT_BYTES + (size_t)COUT * CIN * KK * 4);
    float* pmin = (float*)(ws + OFFT_BYTES + (size_t)2 * COUT * CIN * KK * 4);
    float* pmax = pmin + 1024;
    float* mmin = pmax + 1024;
    float* mmax = mmin + 16;

    __half2* xfft = (__half2*)d_out;   // exactly out_size*4 bytes; overwritten by k_ifft

    hipLaunchKernelGGL(k_reduce1, dim3(1024), dim3(256), 0, stream, xr, xi, pmin, pmax);
    hipLaunchKernelGGL(k_reduce2, dim3(16), dim3(64), 0, stream, pmin, pmax, mmin, mmax);
    hipLaunchKernelGGL(k_kstats, dim3(4096), dim3(64), 0, stream, kr, ki, kmag, kph);
    hipLaunchKernelGGL(k_fwd, dim3(1024), dim3(512), 0, stream, xr, xi, mmin, mmax, xfft);
    hipLaunchKernelGGL(k_gemm, dim3(1024), dim3(256), 0, stream, xfft, kmag, kph, outfft);
    hipLaunchKernelGGL(k_ifft, dim3(1024), dim3(512), 0, stream, outfft, alpha, out);
}

// Round 6
// 262.609 us; speedup vs baseline: 2.7770x; 1.5399x over previous
//
#include <hip/hip_runtime.h>
#include <hip/hip_fp16.h>
#include <hip/hip_bf16.h>
#include <math.h>

#define L 8192
#define LOG2L 13
#define B 16
#define CIN 64
#define COUT 64
#define KK 64

#define PI_F 3.14159265358979323846f

// XOR swizzle for the bit-reversal scatter phase: bijective involution,
// spreads the 32-way bank collision of bitrev-scatter into <=2-way.
__device__ __forceinline__ int swz(int n) { return n ^ ((n >> 8) & 31); }

// ---------------- kernel 1: partial per-batch min/max of |x| ----------------
__global__ __launch_bounds__(256) void k_reduce1(const float* __restrict__ xr,
                                                 const float* __restrict__ xi,
                                                 float* __restrict__ pmin,
                                                 float* __restrict__ pmax) {
    int bid = blockIdx.x;            // 1024 = 16 batches * 64 slices
    int batch = bid >> 6, slice = bid & 63;
    size_t base = (size_t)batch * CIN * L + (size_t)slice * L;
    int tid = threadIdx.x;
    float mn = 3.4e38f, mx = 0.0f;
    for (int r = 0; r < 32; ++r) {
        int idx = r * 256 + tid;
        float a = xr[base + idx], b = xi[base + idx];
        float m = sqrtf(a * a + b * b);
        mn = fminf(mn, m);
        mx = fmaxf(mx, m);
    }
    __shared__ float smn[4], smx[4];
    for (int off = 32; off >= 1; off >>= 1) {
        mn = fminf(mn, __shfl_down(mn, off));
        mx = fmaxf(mx, __shfl_down(mx, off));
    }
    int wave = tid >> 6;
    if ((tid & 63) == 0) { smn[wave] = mn; smx[wave] = mx; }
    __syncthreads();
    if (tid == 0) {
        for (int w = 1; w < 4; ++w) { mn = fminf(mn, smn[w]); mx = fmaxf(mx, smx[w]); }
        pmin[bid] = mn;
        pmax[bid] = mx;
    }
}

// ---------------- kernel 2: final min/max ----------------
__global__ __launch_bounds__(64) void k_reduce2(const float* __restrict__ pmin,
                                                const float* __restrict__ pmax,
                                                float* __restrict__ mmin,
                                                float* __restrict__ mmax) {
    int b = blockIdx.x, t = threadIdx.x;
    float mn = pmin[b * 64 + t], mx = pmax[b * 64 + t];
    for (int off = 32; off >= 1; off >>= 1) {
        mn = fminf(mn, __shfl_down(mn, off));
        mx = fmaxf(mx, __shfl_down(mx, off));
    }
    if (t == 0) { mmin[b] = mn; mmax[b] = mx; }
}

// ---------------- kernel 3: kernel FFT stats (64-pt DFT, mag+phase) ----------------
__global__ __launch_bounds__(64) void k_kstats(const float* __restrict__ kr,
                                               const float* __restrict__ ki,
                                               float* __restrict__ kmag,
                                               float* __restrict__ kph) {
    int row = blockIdx.x;   // o*64 + j  (4096 rows)
    int k = threadIdx.x;    // output frequency 0..63
    __shared__ float sr[64], si[64];
    sr[k] = kr[row * 64 + k];
    si[k] = ki[row * 64 + k];
    __syncthreads();
    float ar = 0.f, ai = 0.f;
    for (int n = 0; n < 64; ++n) {
        int m = (n * k) & 63;                       // exact mod-64 reduction
        float ang = -2.0f * PI_F * (float)m * (1.0f / 64.0f);
        float s, c;
        __sincosf(ang, &s, &c);
        ar += sr[n] * c - si[n] * s;
        ai += sr[n] * s + si[n] * c;
    }
    kmag[row * 64 + k] = sqrtf(ar * ar + ai * ai);
    kph[row * 64 + k] = atan2f(ai, ar);
}

// ---------------- kernel 4: coupling + forward DIF FFT + bitrev permute ----------------
// x_fft written in NATURAL frequency order as half2 into d_out.
__global__ __launch_bounds__(512) void k_fwd(const float* __restrict__ xr,
                                             const float* __restrict__ xi,
                                             const float* __restrict__ mmin_,
                                             const float* __restrict__ mmax_,
                                             __half2* __restrict__ xfft) {
    __shared__ float sRe[L];
    __shared__ float sIm[L];
    int row = blockIdx.x;          // b*64 + j
    int b = row >> 6;
    int tid = threadIdx.x;
    float mmin = mmin_[b], mmax = mmax_[b];
    float span = mmax - mmin;
    float invden = 1.0f / (span + 1e-10f);
    size_t base = (size_t)row * L;

    for (int rpt = 0; rpt < L / 512; ++rpt) {
        int idx = rpt * 512 + tid;
        float a = xr[base + idx], c = xi[base + idx];
        float m = sqrtf(a * a + c * c);
        float xn = (m - mmin) * invden;
#pragma unroll
        for (int it = 0; it < 5; ++it) xn = 3.8f * xn * (1.0f - xn);
        float mc = xn * span + mmin;
        float scale = (m > 0.0f) ? (mc / m) : 0.0f;
        sRe[idx] = a * scale;
        sIm[idx] = c * scale;
    }

    // radix-2 DIF, natural in -> bit-reversed out (storage p holds freq bitrev(p))
    for (int s = 0; s < LOG2L; ++s) {
        int lg = LOG2L - 1 - s;
        int len = 1 << lg;
        float fstep = -PI_F / (float)len;
        __syncthreads();
        for (int rpt = 0; rpt < (L / 2) / 512; ++rpt) {
            int t = rpt * 512 + tid;
            int j = t & (len - 1);
            int idx = ((t >> lg) << (lg + 1)) | j;
            float ar = sRe[idx], ai = sIm[idx];
            float br = sRe[idx + len], bi = sIm[idx + len];
            sRe[idx] = ar + br;
            sIm[idx] = ai + bi;
            float dr = ar - br, di = ai - bi;
            float ang = fstep * (float)j;
            float sn, cs;
            __sincosf(ang, &sn, &cs);
            sRe[idx + len] = dr * cs - di * sn;
            sIm[idx + len] = dr * sn + di * cs;
        }
    }
    __syncthreads();

    // in-LDS bit-reversal permute (swizzled scatter; bijective, race-free)
    float vr[16], vi[16];
#pragma unroll
    for (int r = 0; r < 16; ++r) {
        int idx = r * 512 + tid;
        vr[r] = sRe[idx]; vi[r] = sIm[idx];
    }
    __syncthreads();
#pragma unroll
    for (int r = 0; r < 16; ++r) {
        int idx = r * 512 + tid;
        int n = (int)(__brev((unsigned)idx) >> 19);   // target natural freq
        int a = swz(n);
        sRe[a] = vr[r]; sIm[a] = vi[r];
    }
    __syncthreads();

#pragma unroll
    for (int r = 0; r < 16; ++r) {
        int n = r * 512 + tid;
        int a = swz(n);
        xfft[base + n] = __floats2half2_rn(sRe[a], sIm[a]);
    }
}

// ---------------- kernel 5: per-frequency complex GEMM (natural order) ----------------
// out_fft[b,i,l] = sum_j x_fft[b,j,l] * kint[i,j,l]
// Grid decode: pb = bid & 255, ib = bid >> 8  -> the 4 i-block siblings of a
// p-block land on the same XCD (256 % 8 == 0).
// NOTE: no min-waves clause in launch_bounds. With (256,4) the 128-VGPR cap made
// the allocator demote the 64 f32 accumulators to AGPRs (VGPR_Count=64 observed,
// VALU-busy 3.6x the FMA floor from v_accvgpr_read/write round-trips).
#define PB 32
#define IB 16
#define JC 4
__global__ __launch_bounds__(256) void k_gemm(const __half2* __restrict__ xfft,
                                              const float* __restrict__ kmag,
                                              const float* __restrict__ kph,
                                              __hip_bfloat162* __restrict__ outfft) {
    __shared__ float2 xtile[JC][B][PB];    // 16 KB
    __shared__ float2 ktile[JC][IB][PB];   // 16 KB

    int bid = blockIdx.x;
    int ib = bid >> 8;             // 0..3
    int pb = bid & 255;
    int p0 = pb * PB;
    int i0 = ib * IB;
    int tid = threadIdx.x;
    int pl = tid & 31;             // p lane
    int gi = (tid >> 5) & 3;       // i-group: 4 i's each
    int gb = tid >> 7;             // b-group: 8 b's each
    int p = p0 + pl;
    int l = p;                     // natural frequency order

    // interpolation parameters (i0k/i1k wave-uniform within the block)
    float pos = ((float)l + 0.5f) * ((float)KK / (float)L) - 0.5f;
    pos = fminf(fmaxf(pos, 0.0f), (float)(KK - 1));
    int i0k = (int)floorf(pos);
    int i1k = min(i0k + 1, KK - 1);
    float w = pos - (float)i0k;

    float accR[8][4], accI[8][4];
#pragma unroll
    for (int bb = 0; bb < 8; ++bb)
#pragma unroll
        for (int q = 0; q < 4; ++q) { accR[bb][q] = 0.f; accI[bb][q] = 0.f; }

    // prefetch chunk 0 (8 coalesced half2 loads into regs)
    __half2 px[8];
#pragma unroll
    for (int r = 0; r < 8; ++r) {
        int lin = r * 256 + tid;
        int bj = lin >> 5;
        int jj = bj >> 4;
        int bb = bj & 15;
        px[r] = xfft[((size_t)(bb * CIN + jj)) * L + p0 + pl];
    }

    for (int jc = 0; jc < CIN; jc += JC) {
        __syncthreads();
        // commit prefetched x to LDS
#pragma unroll
        for (int r = 0; r < 8; ++r) {
            int lin = r * 256 + tid;
            int bj = lin >> 5;
            int jj = bj >> 4;
            int bb = bj & 15;
            xtile[jj][bb][pl] = make_float2(__low2float(px[r]), __high2float(px[r]));
        }
        // issue next chunk's prefetch (drains during this chunk's MAC)
        if (jc + JC < CIN) {
#pragma unroll
            for (int r = 0; r < 8; ++r) {
                int lin = r * 256 + tid;
                int bj = lin >> 5;
                int jj = bj >> 4;
                int bb = bj & 15;
                px[r] = xfft[((size_t)(bb * CIN + jc + JC + jj)) * L + p0 + pl];
            }
        }
        // kint: wave-uniform broadcast table loads + per-lane sincos
#pragma unroll
        for (int r = 0; r < 8; ++r) {
            int lin = r * 256 + tid;
            int ij = lin >> 5;
            int jj = ij >> 4;
            int ii = ij & 15;
            int kb = ((i0 + ii) * CIN + jc + jj) * KK;
            float m0 = kmag[kb + i0k], m1 = kmag[kb + i1k];
            float q0 = kph[kb + i0k],  q1 = kph[kb + i1k];
            float mm = m0 + (m1 - m0) * w;
            float ph = q0 + (q1 - q0) * w;
            float sn, cs;
            __sincosf(ph, &sn, &cs);
            ktile[jj][ii][pl] = make_float2(mm * cs, mm * sn);
        }
        __syncthreads();

#pragma unroll
        for (int jj = 0; jj < JC; ++jj) {
            float2 kv[4];
#pragma unroll
            for (int q = 0; q < 4; ++q) kv[q] = ktile[jj][gi * 4 + q][pl];
#pragma unroll
            for (int bb = 0; bb < 8; ++bb) {
                float2 x = xtile[jj][gb * 8 + bb][pl];
#pragma unroll
                for (int q = 0; q < 4; ++q) {
                    accR[bb][q] += x.x * kv[q].x - x.y * kv[q].y;
                    accI[bb][q] += x.x * kv[q].y + x.y * kv[q].x;
                }
            }
        }
    }

#pragma unroll
    for (int q = 0; q < 4; ++q) {
        int i = i0 + gi * 4 + q;
#pragma unroll
        for (int bb = 0; bb < 8; ++bb) {
            int bfull = gb * 8 + bb;
            __hip_bfloat162 o;
            o.x = __float2bfloat16(accR[bb][q]);
            o.y = __float2bfloat16(accI[bb][q]);
            outfft[((size_t)(bfull * COUT + i)) * L + p] = o;
        }
    }
}

// ---------------- kernel 6: inverse DIF FFT + bitrev permute + activation ----------------
// input outfft in NATURAL frequency order; DIF inverse (+ twiddles) -> bitrev out,
// then same swizzled permute back to natural; writes real part * act / L.
__global__ __launch_bounds__(512) void k_ifft(const __hip_bfloat162* __restrict__ outfft,
                                              const float* __restrict__ alpha_,
                                              float* __restrict__ out) {
    __shared__ float sRe[L];
    __shared__ float sIm[L];
    int row = blockIdx.x;          // b*64 + i
    int tid = threadIdx.x;
    float alpha = alpha_[0];
    size_t base = (size_t)row * L;

    for (int rpt = 0; rpt < L / 512; ++rpt) {
        int idx = rpt * 512 + tid;
        __hip_bfloat162 v = outfft[base + idx];
        sRe[idx] = __bfloat162float(v.x);
        sIm[idx] = __bfloat162float(v.y);
    }

    // radix-2 DIF with POSITIVE twiddles: natural in -> bit-reversed out, computes N*x
    for (int s = 0; s < LOG2L; ++s) {
        int lg = LOG2L - 1 - s;
        int len = 1 << lg;
        float fstep = PI_F / (float)len;
        __syncthreads();
        for (int rpt = 0; rpt < (L / 2) / 512; ++rpt) {
            int t = rpt * 512 + tid;
            int j = t & (len - 1);
            int idx = ((t >> lg) << (lg + 1)) | j;
            float ar = sRe[idx], ai = sIm[idx];
            float br = sRe[idx + len], bi = sIm[idx + len];
            sRe[idx] = ar + br;
            sIm[idx] = ai + bi;
            float dr = ar - br, di = ai - bi;
            float ang = fstep * (float)j;
            float sn, cs;
            __sincosf(ang, &sn, &cs);
            sRe[idx + len] = dr * cs - di * sn;
            sIm[idx + len] = dr * sn + di * cs;
        }
    }
    __syncthreads();

    // bitrev permute to natural order (swizzled scatter)
    float vr[16], vi[16];
#pragma unroll
    for (int r = 0; r < 16; ++r) {
        int idx = r * 512 + tid;
        vr[r] = sRe[idx]; vi[r] = sIm[idx];
    }
    __syncthreads();
#pragma unroll
    for (int r = 0; r < 16; ++r) {
        int idx = r * 512 + tid;
        int n = (int)(__brev((unsigned)idx) >> 19);
        int a = swz(n);
        sRe[a] = vr[r]; sIm[a] = vi[r];
    }
    __syncthreads();

    const float invN = 1.0f / (float)L;
#pragma unroll
    for (int rpt = 0; rpt < L / 512; ++rpt) {
        int n = rpt * 512 + tid;
        float act = sinf(alpha * (float)n);
        out[base + n] = sRe[swz(n)] * act * invN;   // real part only
    }
}

// ---------------- launch ----------------
extern "C" void kernel_launch(void* const* d_in, const int* in_sizes, int n_in,
                              void* d_out, int out_size, void* d_ws, size_t ws_size,
                              hipStream_t stream) {
    const float* xr = (const float*)d_in[0];
    const float* xi = (const float*)d_in[1];
    const float* kr = (const float*)d_in[2];
    const float* ki = (const float*)d_in[3];
    const float* alpha = (const float*)d_in[4];
    float* out = (float*)d_out;

    // ws layout (total ~35.7 MB):
    //   [0, 33.5MB)   out_fft as bf16x2 (B*COUT*L complex)
    //   then kmag, kph (COUT*CIN*KK f32 each), then reduce scratch
    char* ws = (char*)d_ws;
    size_t OFFT_BYTES = (size_t)B * COUT * L * 4;          // 33,554,432
    __hip_bfloat162* outfft = (__hip_bfloat162*)ws;
    float* kmag = (float*)(ws + OFFT_BYTES);
    float* kph  = (float*)(ws + OFFT_BYTES + (size_t)COUT * CIN * KK * 4);
    float* pmin = (float*)(ws + OFFT_BYTES + (size_t)2 * COUT * CIN * KK * 4);
    float* pmax = pmin + 1024;
    float* mmin = pmax + 1024;
    float* mmax = mmin + 16;

    __half2* xfft = (__half2*)d_out;   // exactly out_size*4 bytes; overwritten by k_ifft

    hipLaunchKernelGGL(k_reduce1, dim3(1024), dim3(256), 0, stream, xr, xi, pmin, pmax);
    hipLaunchKernelGGL(k_reduce2, dim3(16), dim3(64), 0, stream, pmin, pmax, mmin, mmax);
    hipLaunchKernelGGL(k_kstats, dim3(4096), dim3(64), 0, stream, kr, ki, kmag, kph);
    hipLaunchKernelGGL(k_fwd, dim3(1024), dim3(512), 0, stream, xr, xi, mmin, mmax, xfft);
    hipLaunchKernelGGL(k_gemm, dim3(1024), dim3(256), 0, stream, xfft, kmag, kph, outfft);
    hipLaunchKernelGGL(k_ifft, dim3(1024), dim3(512), 0, stream, outfft, alpha, out);
}